// Round 4
// baseline (749.208 us; speedup 1.0000x reference)
//
#include <hip/hip_runtime.h>
#include <stdint.h>
#include <stddef.h>

typedef short s16;
typedef __attribute__((ext_vector_type(8))) short short8;
typedef __attribute__((ext_vector_type(4))) float floatx4;

__device__ __forceinline__ float bf2f(short s) {
    union { float f; uint32_t u; } c; c.u = ((uint32_t)(uint16_t)s) << 16; return c.f;
}
__device__ __forceinline__ short f2bf(float f) {
    union { float f; uint32_t u; } c; c.f = f;
    uint32_t u = c.u;
    u += 0x7fffu + ((u >> 16) & 1u);   // RNE
    return (short)(u >> 16);
}

// ---------------- K_cvt: x fp32 -> bf16 (8 elem / thread) ----------------
__global__ __launch_bounds__(256) void cvt_kernel(const float* __restrict__ src,
                                                  s16* __restrict__ dst) {
    size_t i = (size_t)blockIdx.x * 256 + threadIdx.x;
    const floatx4* s4 = (const floatx4*)src;
    floatx4 a = s4[i * 2], b = s4[i * 2 + 1];
    short8 o;
    o[0] = f2bf(a[0]); o[1] = f2bf(a[1]); o[2] = f2bf(a[2]); o[3] = f2bf(a[3]);
    o[4] = f2bf(b[0]); o[5] = f2bf(b[1]); o[6] = f2bf(b[2]); o[7] = f2bf(b[3]);
    ((short8*)dst)[i] = o;
}

// ------------- K0: transpose weight fp32 (K,N) -> bf16 (N,K) -------------
__global__ __launch_bounds__(256) void transpose_kernel(const float* __restrict__ w,
                                                        s16* __restrict__ wt,
                                                        int K, int N) {
    int idx = blockIdx.x * 256 + threadIdx.x;
    if (idx >= K * N) return;
    int n = idx / K, k = idx - n * K;      // wt[n][k] = w[k][n]; writes coalesced
    wt[idx] = f2bf(w[(size_t)k * N + n]);
}

// row m (0..100351) -> pointer to its 512-ch row inside x (window gather)
__device__ __forceinline__ const s16* x_row_ptr(const s16* xb, int m) {
    int win = m / 49, t = m - win * 49;
    int b = win >> 6, rem = win & 63, hb = rem >> 3, wb = rem & 7;
    int r = t / 7, c = t - r * 7;
    int n = (hb * 7 + r) * 56 + wb * 7 + c;
    return xb + ((size_t)b * 3136 + n) * 512;
}

// ---------------------------------------------------------------------------
// GEMM: 256x128 tile, BK=32, 16x16x32 bf16 MFMA, 256 threads (4 waves, 2Mx2N).
// Wave tile 128x64 (acc[8][4] = 128 regs; fine at 2 waves/SIMD, <=256 comb.).
// RESIZED FOR 2 BLOCKS/CU (the round-3 lesson): 3 LDS buffers x 24 KB = 72 KB
// -> 2 co-resident blocks per CU = two INDEPENDENT barrier domains, so one
// block's LDS-read phase overlaps the other's MFMA phase (m114 mechanism).
// Round-3's single 96 KB block serialized LDS (768 cyc) against MFMA
// (1242 cyc) block-wide -> 30% MfmaUtil ceiling-by-structure.
// 3-buffer counted vmcnt (T4): compute kt from buf[kt%3], stage kt+2 into
// buf[(kt+2)%3] (last read kt-1, fenced by lgkmcnt(0)+barrier). 6 loads per
// thread per K-step -> vmcnt(6) at each boundary; vmcnt(0) only at kt=14.
// LDS slot swizzle (T2, 64 B rows): slot s of row r holds k-block s^((r>>1)&3);
// linear LDS dest, pre-swizzled SOURCE k-offset; reads use quad^((lm>>1)&3).
// Verified round-3: conflicts 1.45e7 -> 0.
// 2 phases/K-step, 16 MFMA each; setprio(1) around MFMA (T5 — now has real
// cross-block role diversity to arbitrate).
// XCD-chunked bijective swizzle (T1): NT consecutive tiles share an A panel.
// MODE 0: A = xbf (window gather), N=1536, out = qkv bf16 (m,1536)
// MODE 1: A = attn (contiguous),   N=512,  out = d_out fp32 (window scatter)
// ---------------------------------------------------------------------------
template <int MODE>
__global__ __launch_bounds__(256, 2) void gemm_kernel(const s16* __restrict__ A,
                                                      const s16* __restrict__ Bt,
                                                      const float* __restrict__ bias,
                                                      void* __restrict__ outp) {
    constexpr int NT  = (MODE == 0) ? 12 : 4;     // N / 128
    constexpr int CPX = (MODE == 0) ? 588 : 196;  // gridDim.x / 8

    const int o  = (blockIdx.x & 7) * CPX + (blockIdx.x >> 3);
    const int tm = o / NT, tn = o - tm * NT;

    const int tid = threadIdx.x, wave = tid >> 6, lane = tid & 63;

    __shared__ s16 lA[3][256 * 32];   // 48 KiB: [row][k-slot], 64 B rows
    __shared__ s16 lB[3][128 * 32];   // 24 KiB

    // staging: one round = 256 threads x 16 B = 64 rows. A: 4 rounds, B: 2.
    // thread -> row = round*64 + (tid>>2), slot = tid&3; LDS dest is linear
    // (per wave: base + lane*16). SOURCE k-block pre-swizzled:
    // slot s of row r <- global block s ^ ((r>>1)&3);
    // (row>>1)&3 == (tid>>3)&3 (row base multiples of 64).
    const int rloc = tid >> 2;                                 // row 0..63
    const int gran = (((tid & 3) ^ ((tid >> 3) & 3)) << 3);    // swizzled src k
    const s16* a_src[4];
    const s16* b_src[2];
#pragma unroll
    for (int i = 0; i < 4; ++i) {
        int row = i * 64 + rloc;
        if (MODE == 0) a_src[i] = x_row_ptr(A, tm * 256 + row) + gran;
        else           a_src[i] = A + (size_t)(tm * 256 + row) * 512 + gran;
    }
#pragma unroll
    for (int i = 0; i < 2; ++i) {
        int row = i * 64 + rloc;
        b_src[i] = Bt + (size_t)(tn * 128 + row) * 512 + gran;
    }

#define STAGE_A(buf, i)                                                         \
    do {                                                                        \
        __builtin_amdgcn_global_load_lds(                                       \
            (const __attribute__((address_space(1))) void*)a_src[i],            \
            (__attribute__((address_space(3))) void*)&lA[buf][(i) * 2048 + wave * 512], \
            16, 0, 0);                                                          \
        a_src[i] += 32;                                                         \
    } while (0)
#define STAGE_B(buf, i)                                                         \
    do {                                                                        \
        __builtin_amdgcn_global_load_lds(                                       \
            (const __attribute__((address_space(1))) void*)b_src[i],            \
            (__attribute__((address_space(3))) void*)&lB[buf][(i) * 2048 + wave * 512], \
            16, 0, 0);                                                          \
        b_src[i] += 32;                                                         \
    } while (0)

    floatx4 acc[8][4];
#pragma unroll
    for (int mt = 0; mt < 8; ++mt)
#pragma unroll
        for (int nt = 0; nt < 4; ++nt)
            acc[mt][nt] = (floatx4){0.f, 0.f, 0.f, 0.f};

    const int wm = wave >> 1, wn = wave & 1;     // 2M x 2N wave grid
    const int lm = lane & 15, quad = lane >> 4;
    // fragment read: k-block quad lives in LDS slot quad ^ ((lm>>1)&3)
    const int swz = ((quad ^ ((lm >> 1) & 3)) << 3);   // s16 offset in row

    // prologue: stage kt=0 and kt=1 (12 loads), wait until kt0's 6 land
    STAGE_A(0, 0); STAGE_A(0, 1); STAGE_A(0, 2); STAGE_A(0, 3);
    STAGE_B(0, 0); STAGE_B(0, 1);
    STAGE_A(1, 0); STAGE_A(1, 1); STAGE_A(1, 2); STAGE_A(1, 3);
    STAGE_B(1, 0); STAGE_B(1, 1);
    asm volatile("s_waitcnt vmcnt(6)" ::: "memory");
    __builtin_amdgcn_s_barrier();
    __builtin_amdgcn_sched_barrier(0);

#pragma unroll
    for (int kt = 0; kt < 16; ++kt) {
        const int cur = kt % 3, nxt = (kt + 2) % 3;

        // ---------------- phase 0: mt 0..3 ----------------
        short8 bq[4], af[4];
#pragma unroll
        for (int nt = 0; nt < 4; ++nt)
            bq[nt] = *(const short8*)&lB[cur][(wn * 64 + nt * 16 + lm) * 32 + swz];
#pragma unroll
        for (int mt = 0; mt < 4; ++mt)
            af[mt] = *(const short8*)&lA[cur][(wm * 128 + mt * 16 + lm) * 32 + swz];
        if (kt < 14) { STAGE_A(nxt, 0); STAGE_A(nxt, 1); STAGE_A(nxt, 2); }

        __builtin_amdgcn_s_barrier();
        asm volatile("s_waitcnt lgkmcnt(0)" ::: "memory");
        __builtin_amdgcn_sched_barrier(0);

        __builtin_amdgcn_s_setprio(1);
#pragma unroll
        for (int mt = 0; mt < 4; ++mt)
#pragma unroll
            for (int nt = 0; nt < 4; ++nt)
                acc[mt][nt] = __builtin_amdgcn_mfma_f32_16x16x32_bf16(
                    af[mt], bq[nt], acc[mt][nt], 0, 0, 0);
        __builtin_amdgcn_s_setprio(0);
        __builtin_amdgcn_s_barrier();
        __builtin_amdgcn_sched_barrier(0);

        // ---------------- phase 1: mt 4..7 ----------------
        short8 ag[4];
#pragma unroll
        for (int mt = 0; mt < 4; ++mt)
            ag[mt] = *(const short8*)&lA[cur][(wm * 128 + (mt + 4) * 16 + lm) * 32 + swz];
        if (kt < 14) { STAGE_A(nxt, 3); STAGE_B(nxt, 0); STAGE_B(nxt, 1); }

        __builtin_amdgcn_s_barrier();
        asm volatile("s_waitcnt lgkmcnt(0)" ::: "memory");
        __builtin_amdgcn_sched_barrier(0);

        __builtin_amdgcn_s_setprio(1);
#pragma unroll
        for (int mt = 0; mt < 4; ++mt)
#pragma unroll
            for (int nt = 0; nt < 4; ++nt)
                acc[mt + 4][nt] = __builtin_amdgcn_mfma_f32_16x16x32_bf16(
                    ag[mt], bq[nt], acc[mt + 4][nt], 0, 0, 0);
        __builtin_amdgcn_s_setprio(0);

        if (kt < 14)       asm volatile("s_waitcnt vmcnt(6)" ::: "memory");
        else if (kt == 14) asm volatile("s_waitcnt vmcnt(0)" ::: "memory");
        if (kt != 15) {
            __builtin_amdgcn_s_barrier();
            __builtin_amdgcn_sched_barrier(0);
        }
    }
#undef STAGE_A
#undef STAGE_B

    // ---- epilogue: C/D layout col = lane&15, row = quad*4 + reg ----
    float bv[4];
#pragma unroll
    for (int nt = 0; nt < 4; ++nt)
        bv[nt] = bias[tn * 128 + wn * 64 + nt * 16 + lm];

#pragma unroll
    for (int mt = 0; mt < 8; ++mt) {
        int mbase = tm * 256 + wm * 128 + mt * 16 + quad * 4;
#pragma unroll
        for (int i = 0; i < 4; ++i) {
            int m = mbase + i;
            size_t rowoff;
            if (MODE == 1) {
                int win = m / 49, t = m - win * 49;
                int b = win >> 6, rem = win & 63, hb = rem >> 3, wb = rem & 7;
                int r = t / 7, c = t - r * 7;
                int n = (hb * 7 + r) * 56 + wb * 7 + c;
                rowoff = ((size_t)b * 3136 + n) * 512;
            } else {
                rowoff = (size_t)m * 1536;
            }
#pragma unroll
            for (int nt = 0; nt < 4; ++nt) {
                int coln = tn * 128 + wn * 64 + nt * 16 + lm;
                float v = acc[mt][nt][i] + bv[nt];
                if (MODE == 0) ((s16*)outp)[rowoff + coln] = f2bf(v);
                else           ((float*)outp)[rowoff + coln] = v;
            }
        }
    }
}

// --------- K2: per-(win,token) 8x8 head attention; 1 wave / row ----------
// qkv row m: [0,512)=q (h*64+d), [512,1024)=k, [1024,1536)=v
// out layout: attn[win*25088 + h*3136 + t*64 + d]  (== (m,512) rows for proj)
__global__ __launch_bounds__(256) void attn_kernel(const s16* __restrict__ qkv,
                                                   s16* __restrict__ attn) {
    const int tid = threadIdx.x, wave = tid >> 6, lane = tid & 63;
    const int m = blockIdx.x * 4 + wave;   // grid 25088 * 4 = 100352 exact

    __shared__ s16 sh[4][1536];
    s16* my = sh[wave];
    const s16* row = qkv + (size_t)m * 1536;
#pragma unroll
    for (int i = 0; i < 3; ++i)
        *(short8*)&my[i * 512 + lane * 8] = *(const short8*)&row[i * 512 + lane * 8];
    __syncthreads();

    const int h = lane >> 3, g = lane & 7;
    const s16* qs = my + h * 64;
    const s16* ks = my + 512 + g * 64;
    const s16* vs = my + 1024;

    // S[h][g] = (q_h . k_g) / 8 ; d-rotation by h avoids LDS bank conflicts
    float s = 0.f;
#pragma unroll
    for (int db = 0; db < 8; ++db) {
        int d0 = ((db + h) & 7) * 8;
        short8 q8 = *(const short8*)&qs[d0];
        short8 k8 = *(const short8*)&ks[d0];
#pragma unroll
        for (int j = 0; j < 8; ++j) s += bf2f(q8[j]) * bf2f(k8[j]);
    }
    s *= 0.125f;

    // softmax over g within each 8-lane group
    float mx = s;
    mx = fmaxf(mx, __shfl_xor(mx, 1));
    mx = fmaxf(mx, __shfl_xor(mx, 2));
    mx = fmaxf(mx, __shfl_xor(mx, 4));
    float p = __expf(s - mx);
    float sum = p;
    sum += __shfl_xor(sum, 1);
    sum += __shfl_xor(sum, 2);
    sum += __shfl_xor(sum, 4);
    p /= sum;

    // O[h][d0..d0+7], d0 = (lane&7)*8 ; p[h][gg] lives in lane h*8+gg
    float o[8];
#pragma unroll
    for (int j = 0; j < 8; ++j) o[j] = 0.f;
    const int dgrp = (lane & 7) * 8;
#pragma unroll
    for (int gg = 0; gg < 8; ++gg) {
        float pg = __shfl(p, h * 8 + gg);
        short8 v8 = *(const short8*)&vs[gg * 64 + dgrp];
#pragma unroll
        for (int j = 0; j < 8; ++j) o[j] += pg * bf2f(v8[j]);
    }

    int win = m / 49, t = m - win * 49;
    s16* dst = attn + (size_t)win * 25088 + h * 3136 + t * 64 + dgrp;
    short8 ob;
#pragma unroll
    for (int j = 0; j < 8; ++j) ob[j] = f2bf(o[j]);
    *(short8*)dst = ob;
}

extern "C" void kernel_launch(void* const* d_in, const int* in_sizes, int n_in,
                              void* d_out, int out_size, void* d_ws, size_t ws_size,
                              hipStream_t stream) {
    const float* x      = (const float*)d_in[0];
    const float* w_qkv  = (const float*)d_in[1];
    const float* b_qkv  = (const float*)d_in[2];
    const float* w_proj = (const float*)d_in[3];
    const float* b_proj = (const float*)d_in[4];

    char* ws = (char*)d_ws;
    // 102,760,448 B = 100352*512*2 ; 308,281,344 B = 100352*1536*2
    s16* xbf    = (s16*)ws;
    s16* qkv    = (s16*)(ws + 102760448ull);
    s16* attn   = (s16*)(ws + 102760448ull + 308281344ull);
    s16* wqkvT  = (s16*)(ws + 102760448ull + 308281344ull + 102760448ull);
    s16* wprojT = (s16*)(ws + 102760448ull + 308281344ull + 102760448ull + 1572864ull);

    cvt_kernel<<<25088, 256, 0, stream>>>(x, xbf);                       // 51.4M elems
    transpose_kernel<<<3072, 256, 0, stream>>>(w_qkv, wqkvT, 512, 1536);
    transpose_kernel<<<1024, 256, 0, stream>>>(w_proj, wprojT, 512, 512);
    gemm_kernel<0><<<392 * 12, 256, 0, stream>>>(xbf, wqkvT, b_qkv, qkv);
    attn_kernel<<<25088, 256, 0, stream>>>(qkv, attn);
    gemm_kernel<1><<<392 * 4, 256, 0, stream>>>(attn, wprojT, b_proj, d_out);
}

// Round 5
// 707.820 us; speedup vs baseline: 1.0585x; 1.0585x over previous
//
#include <hip/hip_runtime.h>
#include <stdint.h>
#include <stddef.h>

typedef short s16;
typedef __attribute__((ext_vector_type(8))) short short8;
typedef __attribute__((ext_vector_type(4))) float floatx4;

__device__ __forceinline__ float bf2f(short s) {
    union { float f; uint32_t u; } c; c.u = ((uint32_t)(uint16_t)s) << 16; return c.f;
}
__device__ __forceinline__ short f2bf(float f) {
    union { float f; uint32_t u; } c; c.f = f;
    uint32_t u = c.u;
    u += 0x7fffu + ((u >> 16) & 1u);   // RNE
    return (short)(u >> 16);
}

// 8x fp32 -> 8x bf16 via hardware packed cvt (RNE, matches f2bf)
__device__ __forceinline__ short8 cvt8(floatx4 a, floatx4 b) {
    union { uint32_t u[4]; short8 s; } r;
    asm("v_cvt_pk_bf16_f32 %0, %1, %2" : "=v"(r.u[0]) : "v"(a[0]), "v"(a[1]));
    asm("v_cvt_pk_bf16_f32 %0, %1, %2" : "=v"(r.u[1]) : "v"(a[2]), "v"(a[3]));
    asm("v_cvt_pk_bf16_f32 %0, %1, %2" : "=v"(r.u[2]) : "v"(b[0]), "v"(b[1]));
    asm("v_cvt_pk_bf16_f32 %0, %1, %2" : "=v"(r.u[3]) : "v"(b[2]), "v"(b[3]));
    return r.s;
}

// ------------- K0: LDS-tiled transpose fp32 (K,N) -> bf16 (N,K) ------------
// 32x32 tiles; both global read and write fully coalesced (old version read
// at stride N*4B -> ~16x fetch amplification on a tiny kernel).
__global__ __launch_bounds__(256) void transpose_kernel(const float* __restrict__ w,
                                                        s16* __restrict__ wt,
                                                        int K, int N) {
    __shared__ s16 t[32][33];
    const int ntile = N >> 5;
    const int bk = blockIdx.x / ntile, bn = blockIdx.x - bk * ntile;
    const int r = threadIdx.x >> 5, c = threadIdx.x & 31;
#pragma unroll
    for (int i = 0; i < 4; ++i) {
        int k = bk * 32 + r + i * 8;
        t[r + i * 8][c] = f2bf(w[(size_t)k * N + bn * 32 + c]);
    }
    __syncthreads();
#pragma unroll
    for (int i = 0; i < 4; ++i) {
        int n = bn * 32 + r + i * 8;
        wt[(size_t)n * K + bk * 32 + c] = t[c][r + i * 8];
    }
}

// row m (0..100351) -> element offset of its 512-ch row inside x (window gather)
__device__ __forceinline__ size_t x_row_off(int m) {
    int win = m / 49, t = m - win * 49;
    int b = win >> 6, rem = win & 63, hb = rem >> 3, wb = rem & 7;
    int r = t / 7, c = t - r * 7;
    int n = (hb * 7 + r) * 56 + wb * 7 + c;
    return ((size_t)b * 3136 + n) * 512;
}

// ---------------------------------------------------------------------------
// GEMM: 256x256 tile, BK=32, 16x16x32 bf16 MFMA, 512 threads (8 waves).
// Wave tile 128x64: wm=wave&1 (A half), wn=wave>>1 (B quarter). acc[8][4].
// == Round-3 verified structure (221 us, MfmaUtil 30%, conflicts 0) ==
// 3 LDS buffers (96 KiB), compute kt from buf[kt%3], stage kt+2 into
// buf[(kt+2)%3]; 2 phases/K-step, 16 MFMA each; counted vmcnt at boundaries
// (vmcnt(0) only at kt=14); LDS slot swizzle: slot s of row r holds k-block
// s^((r>>1)&3) -> conflict-free b128 reads (verified: 1.45e7 -> 0).
// == New in this round: cvt fused into MODE 0 ==
// MODE 0 A-staging reads x fp32 DIRECTLY (kills the 308 MB cvt round trip):
// phase 0 issues 4 global_load_dwordx4 (fp32, linear k), phase 1 converts via
// v_cvt_pk_bf16_f32 and ds_write_b128 to the SWIZZLED slot (reg-staging lets
// us swizzle at the write; source stays linear). A-regs drain at the ds_write
// (in-order vmcnt => also drains B(kt+1)); B glds issue AFTER the A-writes so
// the boundary vmcnt(2) leaves exactly B(kt+2) in flight.
// MODE 1 keeps the round-3 gload_lds path for A (bf16 src, source-swizzled),
// boundary vmcnt(4).
// XCD-chunked bijective swizzle (T1): NT consecutive tiles share an A panel.
// MODE 0: A = x fp32 (window gather), N=1536, out = qkv bf16 (m,1536)
// MODE 1: A = attn bf16 (contiguous), N=512,  out = d_out fp32 (window scatter)
// ---------------------------------------------------------------------------
template <int MODE>
__global__ __launch_bounds__(512, 2) void gemm_kernel(const void* __restrict__ A,
                                                      const s16* __restrict__ Bt,
                                                      const float* __restrict__ bias,
                                                      void* __restrict__ outp) {
    constexpr int NT  = (MODE == 0) ? 6 : 2;      // N / 256
    constexpr int CPX = (MODE == 0) ? 294 : 98;   // gridDim.x / 8

    const int o  = (blockIdx.x & 7) * CPX + (blockIdx.x >> 3);
    const int tm = o / NT, tn = o - tm * NT;

    const int tid = threadIdx.x, wave = tid >> 6, lane = tid & 63;

    __shared__ s16 lA[3][256 * 32];   // 48 KiB: [row][k-slot], 64 B rows
    __shared__ s16 lB[3][256 * 32];   // 48 KiB

    // swizzled slot offset (s16): slot s of row r holds k-block s^((r>>1)&3);
    // for both staging mappings below, (row>>1)&3 == (tid>>3)&3.
    const int gran = (((tid & 3) ^ ((tid >> 3) & 3)) << 3);

    // ---- B staging (both modes) + MODE1 A staging: gload_lds, src-swizzled
    const int rloc = wave * 16 + (lane >> 2);    // row within 128-row round
    const s16* b_src[2];
#pragma unroll
    for (int i = 0; i < 2; ++i)
        b_src[i] = Bt + (size_t)(tn * 256 + i * 128 + rloc) * 512 + gran;

    // ---- MODE0 A staging: fp32 reg-staged (row tid>>2 and +128, k linear)
    const float* pa0 = nullptr;
    const float* pa1 = nullptr;
    const int arow0 = tid >> 2;                  // 0..127
    if (MODE == 0) {
        const float* xf = (const float*)A;
        const int g8 = (tid & 3) * 8;            // linear k offset (elements)
        pa0 = xf + x_row_off(tm * 256 + arow0) + g8;
        pa1 = xf + x_row_off(tm * 256 + arow0 + 128) + g8;
    }
    // ---- MODE1 A staging: bf16 gload_lds, src-swizzled
    const s16* a_src[2];
    if (MODE == 1) {
#pragma unroll
        for (int i = 0; i < 2; ++i)
            a_src[i] = (const s16*)A + (size_t)(tm * 256 + i * 128 + rloc) * 512 + gran;
    }

#define STAGE_A_LDS(buf, i)                                                     \
    do {                                                                        \
        __builtin_amdgcn_global_load_lds(                                       \
            (const __attribute__((address_space(1))) void*)a_src[i],            \
            (__attribute__((address_space(3))) void*)&lA[buf][(i) * 4096 + wave * 512], \
            16, 0, 0);                                                          \
        a_src[i] += 32;                                                         \
    } while (0)
#define STAGE_B(buf, i)                                                         \
    do {                                                                        \
        __builtin_amdgcn_global_load_lds(                                       \
            (const __attribute__((address_space(1))) void*)b_src[i],            \
            (__attribute__((address_space(3))) void*)&lB[buf][(i) * 4096 + wave * 512], \
            16, 0, 0);                                                          \
        b_src[i] += 32;                                                         \
    } while (0)
// MODE0: load fp32 A for one K-step into regs (issue-early)
#define LOAD_A_F32()                                                            \
    do {                                                                        \
        pv0 = *(const floatx4*)pa0; pv1 = *(const floatx4*)(pa0 + 4);           \
        pv2 = *(const floatx4*)pa1; pv3 = *(const floatx4*)(pa1 + 4);           \
        pa0 += 32; pa1 += 32;                                                   \
    } while (0)
// MODE0: convert + write to swizzled LDS slots (write-late)
#define WRITE_A_F32(buf)                                                        \
    do {                                                                        \
        *(short8*)&lA[buf][arow0 * 32 + gran] = cvt8(pv0, pv1);                 \
        *(short8*)&lA[buf][(arow0 + 128) * 32 + gran] = cvt8(pv2, pv3);         \
    } while (0)

    floatx4 acc[8][4];
#pragma unroll
    for (int mt = 0; mt < 8; ++mt)
#pragma unroll
        for (int nt = 0; nt < 4; ++nt)
            acc[mt][nt] = (floatx4){0.f, 0.f, 0.f, 0.f};

    const int wm = wave & 1, wn = wave >> 1;     // A half, B quarter
    const int lm = lane & 15, quad = lane >> 4;
    const int swz = ((quad ^ ((lm >> 1) & 3)) << 3);   // read-side slot swizzle

    // ---------------- prologue: stage kt=0 and kt=1 ----------------
    {
        floatx4 pv0 = {0,0,0,0}, pv1 = {0,0,0,0}, pv2 = {0,0,0,0}, pv3 = {0,0,0,0};
        if (MODE == 0) {
            LOAD_A_F32(); WRITE_A_F32(0);
            STAGE_B(0, 0); STAGE_B(0, 1);
            LOAD_A_F32(); WRITE_A_F32(1);
            STAGE_B(1, 0); STAGE_B(1, 1);
            asm volatile("s_waitcnt vmcnt(2)" ::: "memory");   // B(0) landed
        } else {
            STAGE_A_LDS(0, 0); STAGE_A_LDS(0, 1); STAGE_B(0, 0); STAGE_B(0, 1);
            STAGE_A_LDS(1, 0); STAGE_A_LDS(1, 1); STAGE_B(1, 0); STAGE_B(1, 1);
            asm volatile("s_waitcnt vmcnt(4)" ::: "memory");   // kt0 landed
        }
        asm volatile("s_waitcnt lgkmcnt(0)" ::: "memory");     // A writes visible
        __builtin_amdgcn_s_barrier();
        __builtin_amdgcn_sched_barrier(0);
    }

#pragma unroll
    for (int kt = 0; kt < 16; ++kt) {
        const int cur = kt % 3, nxt = (kt + 2) % 3;
        floatx4 pv0 = {0,0,0,0}, pv1 = {0,0,0,0}, pv2 = {0,0,0,0}, pv3 = {0,0,0,0};

        // ---------------- phase 0: mt 0..3 ----------------
        short8 bq[4], af[4];
#pragma unroll
        for (int nt = 0; nt < 4; ++nt)
            bq[nt] = *(const short8*)&lB[cur][(wn * 64 + nt * 16 + lm) * 32 + swz];
#pragma unroll
        for (int mt = 0; mt < 4; ++mt)
            af[mt] = *(const short8*)&lA[cur][(wm * 128 + mt * 16 + lm) * 32 + swz];
        if (kt < 14) {
            if (MODE == 0) { LOAD_A_F32(); }                  // issue-early (T14)
            else           { STAGE_A_LDS(nxt, 0); STAGE_A_LDS(nxt, 1); }
        }

        __builtin_amdgcn_s_barrier();
        asm volatile("s_waitcnt lgkmcnt(0)" ::: "memory");
        __builtin_amdgcn_sched_barrier(0);

        __builtin_amdgcn_s_setprio(1);
#pragma unroll
        for (int mt = 0; mt < 4; ++mt)
#pragma unroll
            for (int nt = 0; nt < 4; ++nt)
                acc[mt][nt] = __builtin_amdgcn_mfma_f32_16x16x32_bf16(
                    af[mt], bq[nt], acc[mt][nt], 0, 0, 0);
        __builtin_amdgcn_s_setprio(0);
        __builtin_amdgcn_s_barrier();
        __builtin_amdgcn_sched_barrier(0);

        // ---------------- phase 1: mt 4..7 ----------------
        short8 ag[4];
#pragma unroll
        for (int mt = 0; mt < 4; ++mt)
            ag[mt] = *(const short8*)&lA[cur][(wm * 128 + (mt + 4) * 16 + lm) * 32 + swz];
        if (kt < 14) {
            if (MODE == 0) { WRITE_A_F32(nxt); }              // write-late
            STAGE_B(nxt, 0); STAGE_B(nxt, 1);                 // after A writes
        }

        __builtin_amdgcn_s_barrier();
        asm volatile("s_waitcnt lgkmcnt(0)" ::: "memory");
        __builtin_amdgcn_sched_barrier(0);

        __builtin_amdgcn_s_setprio(1);
#pragma unroll
        for (int mt = 0; mt < 4; ++mt)
#pragma unroll
            for (int nt = 0; nt < 4; ++nt)
                acc[mt + 4][nt] = __builtin_amdgcn_mfma_f32_16x16x32_bf16(
                    ag[mt], bq[nt], acc[mt + 4][nt], 0, 0, 0);
        __builtin_amdgcn_s_setprio(0);

        if (kt < 14) {
            if (MODE == 0) asm volatile("s_waitcnt vmcnt(2)" ::: "memory");
            else           asm volatile("s_waitcnt vmcnt(4)" ::: "memory");
        } else if (kt == 14) {
            asm volatile("s_waitcnt vmcnt(0)" ::: "memory");
        }
        if (kt != 15) {
            __builtin_amdgcn_s_barrier();
            __builtin_amdgcn_sched_barrier(0);
        }
    }
#undef STAGE_A_LDS
#undef STAGE_B
#undef LOAD_A_F32
#undef WRITE_A_F32

    // ---- epilogue: C/D layout col = lane&15, row = quad*4 + reg ----
    float bv[4];
#pragma unroll
    for (int nt = 0; nt < 4; ++nt)
        bv[nt] = bias[tn * 256 + wn * 64 + nt * 16 + lm];

#pragma unroll
    for (int mt = 0; mt < 8; ++mt) {
        int mbase = tm * 256 + wm * 128 + mt * 16 + quad * 4;
#pragma unroll
        for (int i = 0; i < 4; ++i) {
            int m = mbase + i;
            size_t rowoff;
            if (MODE == 1) {
                int win = m / 49, t = m - win * 49;
                int b = win >> 6, rem = win & 63, hb = rem >> 3, wb = rem & 7;
                int r = t / 7, c = t - r * 7;
                int n = (hb * 7 + r) * 56 + wb * 7 + c;
                rowoff = ((size_t)b * 3136 + n) * 512;
            } else {
                rowoff = (size_t)m * 1536;
            }
#pragma unroll
            for (int nt = 0; nt < 4; ++nt) {
                int coln = tn * 256 + wn * 64 + nt * 16 + lm;
                float v = acc[mt][nt][i] + bv[nt];
                if (MODE == 0) ((s16*)outp)[rowoff + coln] = f2bf(v);
                else           ((float*)outp)[rowoff + coln] = v;
            }
        }
    }
}

// --------- K2: per-(win,token) 8x8 head attention; 1 wave / row ----------
// qkv row m: [0,512)=q (h*64+d), [512,1024)=k, [1024,1536)=v
// out layout: attn[win*25088 + h*3136 + t*64 + d]  (== (m,512) rows for proj)
__global__ __launch_bounds__(256) void attn_kernel(const s16* __restrict__ qkv,
                                                   s16* __restrict__ attn) {
    const int tid = threadIdx.x, wave = tid >> 6, lane = tid & 63;
    const int m = blockIdx.x * 4 + wave;   // grid 25088 * 4 = 100352 exact

    __shared__ s16 sh[4][1536];
    s16* my = sh[wave];
    const s16* row = qkv + (size_t)m * 1536;
#pragma unroll
    for (int i = 0; i < 3; ++i)
        *(short8*)&my[i * 512 + lane * 8] = *(const short8*)&row[i * 512 + lane * 8];
    __syncthreads();

    const int h = lane >> 3, g = lane & 7;
    const s16* qs = my + h * 64;
    const s16* ks = my + 512 + g * 64;
    const s16* vs = my + 1024;

    // S[h][g] = (q_h . k_g) / 8 ; d-rotation by h avoids LDS bank conflicts
    float s = 0.f;
#pragma unroll
    for (int db = 0; db < 8; ++db) {
        int d0 = ((db + h) & 7) * 8;
        short8 q8 = *(const short8*)&qs[d0];
        short8 k8 = *(const short8*)&ks[d0];
#pragma unroll
        for (int j = 0; j < 8; ++j) s += bf2f(q8[j]) * bf2f(k8[j]);
    }
    s *= 0.125f;

    // softmax over g within each 8-lane group
    float mx = s;
    mx = fmaxf(mx, __shfl_xor(mx, 1));
    mx = fmaxf(mx, __shfl_xor(mx, 2));
    mx = fmaxf(mx, __shfl_xor(mx, 4));
    float p = __expf(s - mx);
    float sum = p;
    sum += __shfl_xor(sum, 1);
    sum += __shfl_xor(sum, 2);
    sum += __shfl_xor(sum, 4);
    p /= sum;

    // O[h][d0..d0+7], d0 = (lane&7)*8 ; p[h][gg] lives in lane h*8+gg
    float o[8];
#pragma unroll
    for (int j = 0; j < 8; ++j) o[j] = 0.f;
    const int dgrp = (lane & 7) * 8;
#pragma unroll
    for (int gg = 0; gg < 8; ++gg) {
        float pg = __shfl(p, h * 8 + gg);
        short8 v8 = *(const short8*)&vs[gg * 64 + dgrp];
#pragma unroll
        for (int j = 0; j < 8; ++j) o[j] += pg * bf2f(v8[j]);
    }

    int win = m / 49, t = m - win * 49;
    s16* dst = attn + (size_t)win * 25088 + h * 3136 + t * 64 + dgrp;
    short8 ob;
#pragma unroll
    for (int j = 0; j < 8; ++j) ob[j] = f2bf(o[j]);
    *(short8*)dst = ob;
}

extern "C" void kernel_launch(void* const* d_in, const int* in_sizes, int n_in,
                              void* d_out, int out_size, void* d_ws, size_t ws_size,
                              hipStream_t stream) {
    const float* x      = (const float*)d_in[0];
    const float* w_qkv  = (const float*)d_in[1];
    const float* b_qkv  = (const float*)d_in[2];
    const float* w_proj = (const float*)d_in[3];
    const float* b_proj = (const float*)d_in[4];

    char* ws = (char*)d_ws;
    // 308,281,344 B = 100352*1536*2 ; 102,760,448 B = 100352*512*2
    s16* qkv    = (s16*)ws;
    s16* attn   = (s16*)(ws + 308281344ull);
    s16* wqkvT  = (s16*)(ws + 308281344ull + 102760448ull);
    s16* wprojT = (s16*)(ws + 308281344ull + 102760448ull + 1572864ull);

    transpose_kernel<<<768, 256, 0, stream>>>(w_qkv, wqkvT, 512, 1536);   // 16x48 tiles
    transpose_kernel<<<256, 256, 0, stream>>>(w_proj, wprojT, 512, 512);  // 16x16 tiles
    gemm_kernel<0><<<392 * 6, 512, 0, stream>>>(x, wqkvT, b_qkv, qkv);
    attn_kernel<<<25088, 256, 0, stream>>>(qkv, attn);
    gemm_kernel<1><<<392 * 2, 512, 0, stream>>>(attn, wprojT, b_proj, d_out);
}